// Round 8
// baseline (207.152 us; speedup 1.0000x reference)
//
#include <hip/hip_runtime.h>
#include <hip/hip_fp16.h>

#define N_NODES 50000
#define N_EDGES 1600000
#define NPAD 50048            // N rounded to 64 (ghost nodes have cnt=0)
#define F_IN 256
#define F_OUT 64
#define ALPHA 0.2f

#define BS 64                 // nodes per aggregate block
#define NBK 782               // ceil(50000/64)
#define NSC 391               // scatter blocks: ceil(E/4096)
#define CAP2 96               // per-node list capacity (mean 32, max~58, +11 sigma)
#define LSTR 100              // LDS words per node; 100%32=4 -> groups on distinct banks

typedef __attribute__((ext_vector_type(8))) short bf16x8;
typedef __attribute__((ext_vector_type(4))) float f32x4;

__device__ inline unsigned short f2bf(float f) {   // RNE fp32->bf16
    unsigned int u = __float_as_uint(f);
    return (unsigned short)((u + 0x7FFFu + ((u >> 16) & 1u)) >> 16);
}
__device__ inline float bf2f(unsigned short b) {
    return __uint_as_float(((unsigned int)b) << 16);
}

// f32 accumulator += f16(lo/hi of u) * f32 s  — one v_fma_mix_f32, no cvt.
__device__ inline void fmix_lo(float& a, unsigned int u, float s) {
    asm("v_fma_mix_f32 %0, %1, %2, %0 op_sel:[0,0,0] op_sel_hi:[1,0,0]"
        : "+v"(a) : "v"(u), "v"(s));
}
__device__ inline void fmix_hi(float& a, unsigned int u, float s) {
    asm("v_fma_mix_f32 %0, %1, %2, %0 op_sel:[1,0,0] op_sel_hi:[1,0,0]"
        : "+v"(a) : "v"(u), "v"(s));
}

// ---------------------------------------------------------------------------
// W prepack (fp32 -> bf16 frag order) + zero per-node counters.
// ---------------------------------------------------------------------------
__global__ __launch_bounds__(256) void gat_wprep(
    const float* __restrict__ W, unsigned short* __restrict__ Wf,
    int* __restrict__ cnt)
{
    const int di = blockIdx.x * 256 + threadIdx.x;   // < 16384
    for (int i = di; i < NPAD; i += 16384) cnt[i] = 0;
    const int j    = di & 7;
    const int lane = (di >> 3) & 63;
    const int tile = di >> 9;           // ks*4 + nt
    const int ks   = tile >> 2;
    const int nt   = tile & 3;
    const int k = ks * 32 + (lane >> 4) * 8 + j;
    const int n = nt * 16 + (lane & 15);
    Wf[di] = f2bf(W[k * F_OUT + n]);
}

// ---------------------------------------------------------------------------
// Fused fat kernel. Blocks [0,NBK) = MFMA gemm; [NBK,NBK+NSC) = direct
// per-node edge scatter (R8: replaces the whole two-level bucket sort).
// ---------------------------------------------------------------------------
__global__ __launch_bounds__(256) void gat_fused(
    const float* __restrict__ x, const unsigned short* __restrict__ Wf,
    const float* __restrict__ a, unsigned short* __restrict__ Whh,
    float* __restrict__ s_src, float* __restrict__ s_dst,
    const int* __restrict__ edge, int* __restrict__ cnt,
    unsigned short* __restrict__ arr16)
{
    __shared__ __align__(16) unsigned char smem[32768];
    const int t = threadIdx.x;

    if (blockIdx.x < NBK) {
        // ---------------- GEMM path ----------------
        unsigned short* Wl = (unsigned short*)smem;   // 32 KB frag-ordered bf16
        {
            const float4* __restrict__ src = (const float4*)Wf;
            float4* dst = (float4*)Wl;
            #pragma unroll
            for (int i = 0; i < 8; ++i) dst[t + i * 256] = src[t + i * 256];
        }
        __syncthreads();

        const int lane = t & 63;
        const int w    = t >> 6;
        const int q    = lane >> 4;
        const int c16  = lane & 15;
        const bf16x8* __restrict__ Wfrag = (const bf16x8*)Wl;

        float av[4], av2[4];
        #pragma unroll
        for (int nt = 0; nt < 4; ++nt) {
            av[nt]  = a[nt * 16 + c16];
            av2[nt] = a[F_OUT + nt * 16 + c16];
        }

        const int c = blockIdx.x;
        const int node0 = c * 64 + w * 16;
        int row = node0 + c16;
        if (row >= N_NODES) row = N_NODES - 1;
        const float4* __restrict__ xp = (const float4*)(x + (size_t)row * F_IN);

        float4 xv[16];
        #pragma unroll
        for (int ks = 0; ks < 8; ++ks) {
            xv[2 * ks]     = xp[ks * 8 + q * 2];
            xv[2 * ks + 1] = xp[ks * 8 + q * 2 + 1];
        }

        f32x4 acc[4];
        #pragma unroll
        for (int nt = 0; nt < 4; ++nt) acc[nt] = (f32x4){0.f, 0.f, 0.f, 0.f};

        #pragma unroll
        for (int ks = 0; ks < 8; ++ks) {
            float xf[8] = {xv[2*ks].x,   xv[2*ks].y,   xv[2*ks].z,   xv[2*ks].w,
                           xv[2*ks+1].x, xv[2*ks+1].y, xv[2*ks+1].z, xv[2*ks+1].w};
            bf16x8 ah, al;
            #pragma unroll
            for (int j = 0; j < 8; ++j) {
                const unsigned short h = f2bf(xf[j]);
                ah[j] = (short)h;
                al[j] = (short)f2bf(xf[j] - bf2f(h));
            }
            #pragma unroll
            for (int nt = 0; nt < 4; ++nt) {
                const bf16x8 bh = Wfrag[(ks * 4 + nt) * 64 + lane];
                acc[nt] = __builtin_amdgcn_mfma_f32_16x16x32_bf16(ah, bh, acc[nt], 0, 0, 0);
                acc[nt] = __builtin_amdgcn_mfma_f32_16x16x32_bf16(al, bh, acc[nt], 0, 0, 0);
            }
        }

        #pragma unroll
        for (int r = 0; r < 4; ++r) {
            const int node = node0 + q * 4 + r;
            float p = 0.f, qq = 0.f;
            #pragma unroll
            for (int nt = 0; nt < 4; ++nt) {
                const float v = acc[nt][r];
                if (node < N_NODES)
                    Whh[(size_t)node * F_OUT + nt * 16 + c16] =
                        __half_as_ushort(__float2half(v));
                p  = fmaf(v, av[nt], p);
                qq = fmaf(v, av2[nt], qq);
            }
            #pragma unroll
            for (int off = 1; off <= 8; off <<= 1) {
                p  += __shfl_xor(p, off);
                qq += __shfl_xor(qq, off);
            }
            if (c16 == 0 && node < N_NODES) { s_src[node] = p; s_dst[node] = qq; }
        }
    } else {
        // ---------------- SCATTER path: 4096 edges/block ----------------
        const int blk = blockIdx.x - NBK;
        const int e0  = blk * 4096;
        #pragma unroll 4
        for (int i = 0; i < 16; ++i) {
            const int e = e0 + i * 256 + t;
            if (e < N_EDGES) {
                const int s = edge[e];
                const int d = edge[N_EDGES + e];
                const int pos = atomicAdd(&cnt[s], 1);
                if (pos < CAP2)
                    arr16[(size_t)s * CAP2 + pos] = (unsigned short)d;
            }
        }
    }
}

// ---------------------------------------------------------------------------
// Pass 2: block per 64 nodes, 512 threads, 8 waves.
// R8: fixed-stride LDS staging (no scans, no LDS atomics, no overflow):
// slot s -> (n = s/LSTR, o = s%LSTR); real slots compute ee from arr16,
// pad slots write 0 (guard-free gather). Gather = R7's 8-lane groups.
// ---------------------------------------------------------------------------
__global__ __launch_bounds__(512) void gat_aggregate(
    const int* __restrict__ cnt, const unsigned short* __restrict__ arr16,
    const float* __restrict__ s_src, const float* __restrict__ s_dst,
    const unsigned short* __restrict__ Whh, float* __restrict__ out)
{
    __shared__ unsigned int ent[BS * LSTR];   // 25.6 KB
    __shared__ int   cl[BS];
    __shared__ float ssf[BS];
    const int t = threadIdx.x;
    const int lane = t & 63;
    const int w = t >> 6;                // 0..7
    const int b = blockIdx.x;

    if (t < BS) {
        cl[t]  = min(cnt[b * BS + t], CAP2);
        ssf[t] = s_src[b * BS + t];      // ghost nodes: cl=0, value unused
    }
    __syncthreads();

    for (int s = t; s < BS * LSTR; s += 512) {   // 12.5 passes, streaming
        const int n = s / LSTR;                   // const-div -> magic mul
        const int o = s - n * LSTR;
        unsigned val = 0u;
        if (o < cl[n]) {
            const int d = arr16[(size_t)(b * BS + n) * CAP2 + o];
            const float sc = ssf[n] + s_dst[d];
            const float ee = __expf(-(sc > 0.f ? sc : ALPHA * sc));
            val = ((unsigned)d << 16) | (unsigned)f2bf(ee);
        }
        ent[s] = val;
    }
    __syncthreads();

    const int q8 = lane >> 3;            // group 0..7 — one node each
    const int f8 = lane & 7;             // uint4 index within Whh row
    const uint4* __restrict__ Whh4 = (const uint4*)Whh;  // row = 8 uint4

    const int n    = w * 8 + q8;
    const int node = b * BS + n;
    const int cn   = (cl[n] + 7) & ~7;   // padded bound; pads are 0 in ent
    const unsigned* __restrict__ ebase = ent + n * LSTR;

    float4 a0 = make_float4(0.f, 0.f, 0.f, 0.f);
    float4 a1 = make_float4(0.f, 0.f, 0.f, 0.f);
    float rsum = 0.f;
    for (int j = 0; j < cn; j += 8) {    // 8 edges/iter/group, no guards
        const uint4* __restrict__ ep = (const uint4*)(ebase + j);
        const uint4 ea = ep[0];
        const uint4 eb = ep[1];
        const unsigned eu[8] = {ea.x, ea.y, ea.z, ea.w, eb.x, eb.y, eb.z, eb.w};
        uint4 wv[8];
        #pragma unroll
        for (int k = 0; k < 8; ++k)
            wv[k] = Whh4[(size_t)(eu[k] >> 16) * 8 + f8];
        #pragma unroll
        for (int k = 0; k < 8; ++k) {
            const float et = __uint_as_float(eu[k] << 16);   // bf16 -> f32
            fmix_lo(a0.x, wv[k].x, et);
            fmix_hi(a0.y, wv[k].x, et);
            fmix_lo(a0.z, wv[k].y, et);
            fmix_hi(a0.w, wv[k].y, et);
            fmix_lo(a1.x, wv[k].z, et);
            fmix_hi(a1.y, wv[k].z, et);
            fmix_lo(a1.z, wv[k].w, et);
            fmix_hi(a1.w, wv[k].w, et);
            rsum += et;
        }
    }
    const float rinv = __builtin_amdgcn_rcpf(rsum);
    float4 v0, v1;
    v0.x = a0.x * rinv; v0.y = a0.y * rinv; v0.z = a0.z * rinv; v0.w = a0.w * rinv;
    v1.x = a1.x * rinv; v1.y = a1.y * rinv; v1.z = a1.z * rinv; v1.w = a1.w * rinv;
    v0.x = v0.x > 0.f ? v0.x : (__expf(v0.x) - 1.f);
    v0.y = v0.y > 0.f ? v0.y : (__expf(v0.y) - 1.f);
    v0.z = v0.z > 0.f ? v0.z : (__expf(v0.z) - 1.f);
    v0.w = v0.w > 0.f ? v0.w : (__expf(v0.w) - 1.f);
    v1.x = v1.x > 0.f ? v1.x : (__expf(v1.x) - 1.f);
    v1.y = v1.y > 0.f ? v1.y : (__expf(v1.y) - 1.f);
    v1.z = v1.z > 0.f ? v1.z : (__expf(v1.z) - 1.f);
    v1.w = v1.w > 0.f ? v1.w : (__expf(v1.w) - 1.f);
    if (node < N_NODES) {
        ((float4*)out)[(size_t)node * 16 + f8 * 2]     = v0;
        ((float4*)out)[(size_t)node * 16 + f8 * 2 + 1] = v1;
    }
}

extern "C" void kernel_launch(void* const* d_in, const int* in_sizes, int n_in,
                              void* d_out, int out_size, void* d_ws, size_t ws_size,
                              hipStream_t stream) {
    const float* x    = (const float*)d_in[0];
    const int*   edge = (const int*)  d_in[1];
    const float* W    = (const float*)d_in[2];
    const float* a    = (const float*)d_in[3];
    float* out = (float*)d_out;

    unsigned short* Whh   = (unsigned short*)d_ws;                      // 3.2M us
    unsigned short* arr16 = Whh + (size_t)N_NODES * F_OUT;              // NPAD*96 us
    float*          s_src = (float*)(arr16 + (size_t)NPAD * CAP2);      // 50,000 f
    float*          s_dst = s_src + N_NODES;                            // 50,000 f
    int*            cnt   = (int*)(s_dst + N_NODES);                    // NPAD i
    unsigned short* Wf    = (unsigned short*)(cnt + NPAD);              // 16,384 us

    gat_wprep<<<64, 256, 0, stream>>>(W, Wf, cnt);
    gat_fused<<<NBK + NSC, 256, 0, stream>>>(x, Wf, a, Whh, s_src, s_dst,
                                             edge, cnt, arr16);
    gat_aggregate<<<NBK, 512, 0, stream>>>(cnt, arr16, s_src, s_dst, Whh, out);
}

// Round 9
// 144.707 us; speedup vs baseline: 1.4315x; 1.4315x over previous
//
#include <hip/hip_runtime.h>
#include <hip/hip_fp16.h>

#define N_NODES 50000
#define N_EDGES 1600000
#define F_IN 256
#define F_OUT 64
#define ALPHA 0.2f

#define BS 64                 // nodes per bucket
#define NBK 782               // ceil(50000/64)
#define NSUB 8                // sub-buckets keyed by bucket-block & 7
#define CAP 384               // per (sub,bucket) capacity; mean 256, sd ~15
#define EB 2048               // edges per bucket-sort block
#define NBB 782               // ceil(E/EB)
#define LDS_CAP 3584          // >= 3072 + 64*7 worst-case padded total
#define OF_CAP 16384          // overflow list (normally empty)

typedef __attribute__((ext_vector_type(8))) short bf16x8;
typedef __attribute__((ext_vector_type(4))) float f32x4;

__device__ inline unsigned short f2bf(float f) {   // RNE fp32->bf16
    unsigned int u = __float_as_uint(f);
    return (unsigned short)((u + 0x7FFFu + ((u >> 16) & 1u)) >> 16);
}
__device__ inline float bf2f(unsigned short b) {
    return __uint_as_float(((unsigned int)b) << 16);
}

// f32 accumulator += f16(lo/hi of u) * f32 s  — one v_fma_mix_f32, no cvt.
__device__ inline void fmix_lo(float& a, unsigned int u, float s) {
    asm("v_fma_mix_f32 %0, %1, %2, %0 op_sel:[0,0,0] op_sel_hi:[1,0,0]"
        : "+v"(a) : "v"(u), "v"(s));
}
__device__ inline void fmix_hi(float& a, unsigned int u, float s) {
    asm("v_fma_mix_f32 %0, %1, %2, %0 op_sel:[1,0,0] op_sel_hi:[1,0,0]"
        : "+v"(a) : "v"(u), "v"(s));
}

// ---------------------------------------------------------------------------
// W prepack (fp32 -> bf16 frag order) + zero cnt/of_cnt.
// ---------------------------------------------------------------------------
__global__ __launch_bounds__(256) void gat_wprep(
    const float* __restrict__ W, unsigned short* __restrict__ Wf,
    int* __restrict__ cnt, int* __restrict__ of_cnt)
{
    const int di = blockIdx.x * 256 + threadIdx.x;   // < 16384
    if (di < NSUB * NBK) cnt[di] = 0;
    if (di == 0) of_cnt[0] = 0;
    const int j    = di & 7;
    const int lane = (di >> 3) & 63;
    const int tile = di >> 9;           // ks*4 + nt
    const int ks   = tile >> 2;
    const int nt   = tile & 3;
    const int k = ks * 32 + (lane >> 4) * 8 + j;
    const int n = nt * 16 + (lane & 15);
    Wf[di] = f2bf(W[k * F_OUT + n]);
}

// ---------------------------------------------------------------------------
// Fused fat kernel. Blocks [0,NBB) = bucket sort; [NBB,NBB+NBK) = MFMA gemm.
// R9: gemm path reads W fragments DIRECTLY from global Wf (32 KB, L1-resident,
// identical across blocks) — no LDS staging, no barrier. smem shrunk to the
// bucket path's 21.7 KB -> LDS no longer caps fused occupancy at 2 blocks/CU.
// ---------------------------------------------------------------------------
__global__ __launch_bounds__(256) void gat_fused(
    const float* __restrict__ x, const unsigned short* __restrict__ Wf,
    const float* __restrict__ a, unsigned short* __restrict__ Whh,
    float* __restrict__ s_src, float* __restrict__ s_dst,
    const int* __restrict__ edge, int* __restrict__ cnt,
    unsigned int* __restrict__ arr, int* __restrict__ of_cnt,
    int2* __restrict__ of_list)
{
    __shared__ __align__(16) unsigned char smem[21732];
    const int t = threadIdx.x;

    if (blockIdx.x >= NBB) {
        // ---------------- GEMM path (LDS-free) ----------------
        const int lane = t & 63;
        const int w    = t >> 6;
        const int q    = lane >> 4;
        const int c16  = lane & 15;
        const bf16x8* __restrict__ Wfrag = (const bf16x8*)Wf;  // global, L1-hot

        float av[4], av2[4];
        #pragma unroll
        for (int nt = 0; nt < 4; ++nt) {
            av[nt]  = a[nt * 16 + c16];
            av2[nt] = a[F_OUT + nt * 16 + c16];
        }

        const int c = blockIdx.x - NBB;
        const int node0 = c * 64 + w * 16;
        int row = node0 + c16;
        if (row >= N_NODES) row = N_NODES - 1;
        const float4* __restrict__ xp = (const float4*)(x + (size_t)row * F_IN);

        float4 xv[16];
        #pragma unroll
        for (int ks = 0; ks < 8; ++ks) {
            xv[2 * ks]     = xp[ks * 8 + q * 2];
            xv[2 * ks + 1] = xp[ks * 8 + q * 2 + 1];
        }

        f32x4 acc[4];
        #pragma unroll
        for (int nt = 0; nt < 4; ++nt) acc[nt] = (f32x4){0.f, 0.f, 0.f, 0.f};

        #pragma unroll
        for (int ks = 0; ks < 8; ++ks) {
            float xf[8] = {xv[2*ks].x,   xv[2*ks].y,   xv[2*ks].z,   xv[2*ks].w,
                           xv[2*ks+1].x, xv[2*ks+1].y, xv[2*ks+1].z, xv[2*ks+1].w};
            bf16x8 ah, al;
            #pragma unroll
            for (int j = 0; j < 8; ++j) {
                const unsigned short h = f2bf(xf[j]);
                ah[j] = (short)h;
                al[j] = (short)f2bf(xf[j] - bf2f(h));
            }
            #pragma unroll
            for (int nt = 0; nt < 4; ++nt) {
                const bf16x8 bh = Wfrag[(ks * 4 + nt) * 64 + lane];
                acc[nt] = __builtin_amdgcn_mfma_f32_16x16x32_bf16(ah, bh, acc[nt], 0, 0, 0);
                acc[nt] = __builtin_amdgcn_mfma_f32_16x16x32_bf16(al, bh, acc[nt], 0, 0, 0);
            }
        }

        #pragma unroll
        for (int r = 0; r < 4; ++r) {
            const int node = node0 + q * 4 + r;
            float p = 0.f, qq = 0.f;
            #pragma unroll
            for (int nt = 0; nt < 4; ++nt) {
                const float v = acc[nt][r];
                if (node < N_NODES)
                    Whh[(size_t)node * F_OUT + nt * 16 + c16] =
                        __half_as_ushort(__float2half(v));
                p  = fmaf(v, av[nt], p);
                qq = fmaf(v, av2[nt], qq);
            }
            #pragma unroll
            for (int off = 1; off <= 8; off <<= 1) {
                p  += __shfl_xor(p, off);
                qq += __shfl_xor(qq, off);
            }
            if (c16 == 0 && node < N_NODES) { s_src[node] = p; s_dst[node] = qq; }
        }
    } else {
        // ---------------- BUCKET path (EB=2048) ----------------
        int* lhist            = (int*)smem;                       // 782
        int* lstart           = (int*)(smem + 3128);              // 783
        int* gbase            = (int*)(smem + 6260);              // 782
        int* cursor           = (int*)(smem + 9388);              // 782
        int* scanbuf          = (int*)(smem + 12516);             // 256
        unsigned int* sorted  = (unsigned int*)(smem + 13540);    // 2048

        const int blk = blockIdx.x;
        const int e0  = blk * EB;
        const int sub = blk & 7;

        for (int i = t; i < NBK; i += 256) lhist[i] = 0;
        __syncthreads();

        int sreg[EB / 256];
        #pragma unroll
        for (int i = 0; i < EB / 256; ++i) {
            const int e = e0 + i * 256 + t;
            int s = -1;
            if (e < N_EDGES) {
                s = edge[e];
                atomicAdd(&lhist[s >> 6], 1);
            }
            sreg[i] = s;
        }
        __syncthreads();

        int psum = 0;
        {
            const int b0 = t * 4;
            #pragma unroll
            for (int i = 0; i < 4; ++i)
                if (b0 + i < NBK) psum += lhist[b0 + i];
        }
        scanbuf[t] = psum;
        __syncthreads();
        for (int off = 1; off < 256; off <<= 1) {
            const int v = (t >= off) ? scanbuf[t - off] : 0;
            __syncthreads();
            scanbuf[t] += v;
            __syncthreads();
        }
        {
            int run = scanbuf[t] - psum;
            const int b0 = t * 4;
            #pragma unroll
            for (int i = 0; i < 4; ++i) {
                const int b = b0 + i;
                if (b < NBK) {
                    lstart[b] = run;
                    cursor[b] = run;
                    run += lhist[b];
                }
            }
            if (t == 255) lstart[NBK] = scanbuf[255];
        }
        __syncthreads();

        for (int b = t; b < NBK; b += 256) {
            const int c = lhist[b];
            gbase[b] = (c > 0) ? atomicAdd(&cnt[sub * NBK + b], c) : 0;
        }

        #pragma unroll
        for (int i = 0; i < EB / 256; ++i) {
            const int s = sreg[i];
            if (s >= 0) {
                const int e = e0 + i * 256 + t;
                const int d = edge[N_EDGES + e];
                const int b = s >> 6;
                const int pos = atomicAdd(&cursor[b], 1);
                sorted[pos] = ((unsigned)b << 22) | ((unsigned)(s & 63) << 16) | (unsigned)d;
            }
        }
        __syncthreads();

        const int C = lstart[NBK];
        for (int p = t; p < C; p += 256) {
            const unsigned en = sorted[p];
            const int b = (int)(en >> 22);
            const int idx = gbase[b] + (p - lstart[b]);
            if (idx < CAP) {
                arr[((size_t)(sub * NBK + b)) * CAP + idx] = en & 0x3FFFFFu;
            } else {
                const int s = b * 64 + (int)((en >> 16) & 63);
                const int op = atomicAdd(of_cnt, 1);
                if (op < OF_CAP) of_list[op] = make_int2(s, (int)(en & 0xFFFFu));
            }
        }
    }
}

// ---------------------------------------------------------------------------
// Pass 2: block per 64-node bucket, 512 threads, 8 waves. (R7-verified:
// packed uint ent2, mult-of-8 padding, 8-lane groups, fma_mix, rcp.)
// ---------------------------------------------------------------------------
__global__ __launch_bounds__(512) void gat_aggregate(
    const int* __restrict__ cnt, const unsigned int* __restrict__ arr,
    const float* __restrict__ s_src, const float* __restrict__ s_dst,
    const unsigned short* __restrict__ Whh, const int* __restrict__ of_cnt,
    const int2* __restrict__ of_list, float* __restrict__ out)
{
    __shared__ unsigned int ent2[LDS_CAP + 8];   // ~14.4 KB
    __shared__ int bin[BS];
    __shared__ int start[BS + 1];
    __shared__ int Pl[NSUB + 1];
    const int t = threadIdx.x;
    const int lane = t & 63;
    const int w = t >> 6;                // 0..7
    const int b = blockIdx.x;

    if (t < BS) bin[t] = 0;
    if (t < 8) ent2[LDS_CAP + t] = 0u;
    if (w == 0) {                        // parallel 8-way cnt scan
        int c = (lane < NSUB) ? min(cnt[lane * NBK + b], CAP) : 0;
        int s = c;
        #pragma unroll
        for (int off = 1; off < NSUB; off <<= 1) {
            const int v = __shfl_up(s, off);
            if (lane >= off) s += v;
        }
        if (lane < NSUB) Pl[lane + 1] = s;
        if (lane == 0)   Pl[0] = 0;
    }
    __syncthreads();
    const int C = Pl[NSUB];              // <= 3072
    const int nof = min(of_cnt[0], OF_CAP);

    unsigned enr[6];
    int nr = 0;
    for (int g = t; g < C; g += 512) {
        int sub = 0;
        #pragma unroll
        for (int s2 = 1; s2 < NSUB; ++s2) sub += (g >= Pl[s2]);
        const unsigned en = arr[((size_t)(sub * NBK + b)) * CAP + (g - Pl[sub])];
        enr[nr++] = en;
        atomicAdd(&bin[en >> 16], 1);
    }
    for (int i = t; i < nof; i += 512) {
        const int2 e2 = of_list[i];
        if ((e2.x >> 6) == b) atomicAdd(&bin[e2.x & 63], 1);
    }
    __syncthreads();
    if (w == 0) {                        // scan over PADDED (mult-of-8) counts
        const int c  = bin[lane];
        const int pc = (c + 7) & ~7;
        int s = pc;
        #pragma unroll
        for (int off = 1; off < BS; off <<= 1) {
            const int v = __shfl_up(s, off);
            if (lane >= off) s += v;
        }
        start[lane + 1] = s;
        if (lane == 0) start[0] = 0;
        bin[lane] = s - pc;              // exclusive padded base = scatter cursor
    }
    __syncthreads();

    for (int r = 0; r < nr; ++r) {
        const unsigned en = enr[r];
        const int sl = (int)(en >> 16);
        const int d  = (int)(en & 0xffffu);
        const float sc = s_src[b * BS + sl] + s_dst[d];
        const float ee = __expf(-(sc > 0.f ? sc : ALPHA * sc));
        const int pos = atomicAdd(&bin[sl], 1);
        if (pos < LDS_CAP) ent2[pos] = ((unsigned)d << 16) | (unsigned)f2bf(ee);
    }
    for (int i = t; i < nof; i += 512) {
        const int2 e2 = of_list[i];
        if ((e2.x >> 6) == b) {
            const float sc = s_src[e2.x] + s_dst[e2.y];
            const float ee = __expf(-(sc > 0.f ? sc : ALPHA * sc));
            const int pos = atomicAdd(&bin[e2.x & 63], 1);
            if (pos < LDS_CAP) ent2[pos] = ((unsigned)e2.y << 16) | (unsigned)f2bf(ee);
        }
    }
    __syncthreads();
    {   // pad-fill: 8 threads per node fill [end, start[n+1]) with 0
        const int n  = t & 63;
        const int e1 = min(start[n + 1], LDS_CAP);
        for (int p = bin[n] + (t >> 6); p < e1; p += 8)
            ent2[p] = 0u;
    }
    __syncthreads();

    const int q8 = lane >> 3;            // group 0..7 — one node each
    const int f8 = lane & 7;             // uint4 index within row (8 halfs)
    const uint4* __restrict__ Whh4 = (const uint4*)Whh;  // row = 8 uint4

    const int n    = w * 8 + q8;
    const int node = b * BS + n;
    const int r0 = start[n];
    const int r1 = min(start[n + 1], LDS_CAP);
    float4 a0 = make_float4(0.f, 0.f, 0.f, 0.f);
    float4 a1 = make_float4(0.f, 0.f, 0.f, 0.f);
    float rsum = 0.f;
    for (int j = r0; j < r1; j += 8) {   // 8 edges/iter/group, no guards
        unsigned eu[8];
        uint4 wv[8];
        #pragma unroll
        for (int k = 0; k < 8; ++k) {
            const unsigned e = ent2[j + k];       // broadcast within group
            eu[k] = e;
            wv[k] = Whh4[(size_t)(e >> 16) * 8 + f8];
        }
        #pragma unroll
        for (int k = 0; k < 8; ++k) {
            const float et = __uint_as_float(eu[k] << 16);   // bf16 -> f32
            fmix_lo(a0.x, wv[k].x, et);
            fmix_hi(a0.y, wv[k].x, et);
            fmix_lo(a0.z, wv[k].y, et);
            fmix_hi(a0.w, wv[k].y, et);
            fmix_lo(a1.x, wv[k].z, et);
            fmix_hi(a1.y, wv[k].z, et);
            fmix_lo(a1.z, wv[k].w, et);
            fmix_hi(a1.w, wv[k].w, et);
            rsum += et;
        }
    }
    const float rinv = __builtin_amdgcn_rcpf(rsum);
    float4 v0, v1;
    v0.x = a0.x * rinv; v0.y = a0.y * rinv; v0.z = a0.z * rinv; v0.w = a0.w * rinv;
    v1.x = a1.x * rinv; v1.y = a1.y * rinv; v1.z = a1.z * rinv; v1.w = a1.w * rinv;
    v0.x = v0.x > 0.f ? v0.x : (__expf(v0.x) - 1.f);
    v0.y = v0.y > 0.f ? v0.y : (__expf(v0.y) - 1.f);
    v0.z = v0.z > 0.f ? v0.z : (__expf(v0.z) - 1.f);
    v0.w = v0.w > 0.f ? v0.w : (__expf(v0.w) - 1.f);
    v1.x = v1.x > 0.f ? v1.x : (__expf(v1.x) - 1.f);
    v1.y = v1.y > 0.f ? v1.y : (__expf(v1.y) - 1.f);
    v1.z = v1.z > 0.f ? v1.z : (__expf(v1.z) - 1.f);
    v1.w = v1.w > 0.f ? v1.w : (__expf(v1.w) - 1.f);
    if (node < N_NODES) {
        ((float4*)out)[(size_t)node * 16 + f8 * 2]     = v0;
        ((float4*)out)[(size_t)node * 16 + f8 * 2 + 1] = v1;
    }
}

extern "C" void kernel_launch(void* const* d_in, const int* in_sizes, int n_in,
                              void* d_out, int out_size, void* d_ws, size_t ws_size,
                              hipStream_t stream) {
    const float* x    = (const float*)d_in[0];
    const int*   edge = (const int*)  d_in[1];
    const float* W    = (const float*)d_in[2];
    const float* a    = (const float*)d_in[3];
    float* out = (float*)d_out;

    unsigned short* Whh   = (unsigned short*)d_ws;                      // 3.2M us
    unsigned int*   arr   = (unsigned int*)(Whh + (size_t)N_NODES * F_OUT);
    float*          s_src = (float*)(arr + (size_t)NSUB * NBK * CAP);   // 50,000 f
    float*          s_dst = s_src + N_NODES;                            // 50,000 f
    int*            cnt   = (int*)(s_dst + N_NODES);                    // 6,256 i
    int2*           of_list = (int2*)(cnt + NSUB * NBK);                // 8B-aligned
    int*            of_cnt  = (int*)(of_list + OF_CAP);                 // 1 i + pad 3
    unsigned short* Wf      = (unsigned short*)(of_cnt + 4);            // 16,384 us

    gat_wprep<<<64, 256, 0, stream>>>(W, Wf, cnt, of_cnt);
    gat_fused<<<NBB + NBK, 256, 0, stream>>>(x, Wf, a, Whh, s_src, s_dst,
                                             edge, cnt, arr, of_cnt, of_list);
    gat_aggregate<<<NBK, 512, 0, stream>>>(cnt, arr, s_src, s_dst, Whh,
                                           of_cnt, of_list, out);
}